// Round 1
// baseline (1221.009 us; speedup 1.0000x reference)
//
#include <hip/hip_runtime.h>
#include <hip/hip_bf16.h>
#include <math.h>

#define Bz 2
#define Tz 2048
#define Cz 1024
#define Hz 16
#define HKVz 4
#define Dz 64
#define GATE_CHz 32
#define QKV_N 1536          // H*D + 2*HKV*D
#define ROWS (Bz*Tz)        // 4096

// ---------------------------------------------------------------------------
// GEMM (NT): Cmat[m][col_off+n] = sum_k A[m][k] * W[n][k]
// A: M x K row-major, W: N x K row-major, Cmat row stride ldc.
// ---------------------------------------------------------------------------
#define BM 64
#define BN 64
#define BK 16

__global__ __launch_bounds__(256) void gemm_nt(const float* __restrict__ A,
                                               const float* __restrict__ W,
                                               float* __restrict__ Cmat,
                                               int M, int N, int K,
                                               int ldc, int col_off)
{
    __shared__ float As[BK][BM + 4];   // transposed: As[k][m], pad keeps 16B align
    __shared__ float Ws[BK][BN + 4];

    const int tid = threadIdx.x;
    const int m0 = blockIdx.y * BM;
    const int n0 = blockIdx.x * BN;
    const int tx = tid & 15;    // n sub-tile
    const int ty = tid >> 4;    // m sub-tile

    float acc[4][4] = {};

    const int lrow = tid >> 2;        // 0..63
    const int lcol = (tid & 3) * 4;   // 0,4,8,12

    for (int k0 = 0; k0 < K; k0 += BK) {
        float4 av = *(const float4*)&A[(size_t)(m0 + lrow) * K + k0 + lcol];
        float4 wv = *(const float4*)&W[(size_t)(n0 + lrow) * K + k0 + lcol];
        As[lcol + 0][lrow] = av.x; As[lcol + 1][lrow] = av.y;
        As[lcol + 2][lrow] = av.z; As[lcol + 3][lrow] = av.w;
        Ws[lcol + 0][lrow] = wv.x; Ws[lcol + 1][lrow] = wv.y;
        Ws[lcol + 2][lrow] = wv.z; Ws[lcol + 3][lrow] = wv.w;
        __syncthreads();
        #pragma unroll
        for (int kk = 0; kk < BK; ++kk) {
            float4 a4 = *(const float4*)&As[kk][ty * 4];
            float4 w4 = *(const float4*)&Ws[kk][tx * 4];
            float aa[4] = {a4.x, a4.y, a4.z, a4.w};
            float ww[4] = {w4.x, w4.y, w4.z, w4.w};
            #pragma unroll
            for (int i = 0; i < 4; ++i)
                #pragma unroll
                for (int j = 0; j < 4; ++j)
                    acc[i][j] = fmaf(aa[i], ww[j], acc[i][j]);
        }
        __syncthreads();
    }

    #pragma unroll
    for (int i = 0; i < 4; ++i) {
        const int m = m0 + ty * 4 + i;
        float4 o = make_float4(acc[i][0], acc[i][1], acc[i][2], acc[i][3]);
        *(float4*)&Cmat[(size_t)m * ldc + col_off + n0 + tx * 4] = o;
    }
}

// ---------------------------------------------------------------------------
// Epilogue: one wave per (row, head-slot).
// slots 0..15  : q head  -> rope + rmsnorm (in place)
// slots 16..19 : k head  -> rope + rmsnorm (in place)
// slots 20..23 : v head  -> v += 2*sigmoid(x[:32] @ Wgate[h]) * ve (in place)
// ---------------------------------------------------------------------------
__global__ __launch_bounds__(256) void epilogue_kernel(float* __restrict__ qkv,
                                                       const float* __restrict__ x,
                                                       const float* __restrict__ ve,
                                                       const float* __restrict__ cosb,
                                                       const float* __restrict__ sinb,
                                                       const float* __restrict__ Wgate)
{
    const int wave = (blockIdx.x * blockDim.x + threadIdx.x) >> 6;
    const int lane = threadIdx.x & 63;
    const int NSLOT = Hz + 2 * HKVz;            // 24
    const int hh = wave % NSLOT;
    const int bt = wave / NSLOT;
    if (bt >= ROWS) return;
    const int t = bt % Tz;
    float* row = qkv + (size_t)bt * QKV_N;

    if (hh < Hz + HKVz) {
        // ---- rope + rms for q/k ----
        float* p = (hh < Hz) ? (row + hh * Dz)
                             : (row + Hz * Dz + (hh - Hz) * Dz);
        float v0 = p[lane];
        float vo = p[lane ^ 32];
        const int dh = lane & 31;
        const float c = cosb[t * 32 + dh];
        const float s = sinb[t * 32 + dh];
        // reference rotation: [x1*c + x2*s, -x1*s + x2*c]
        float r = (lane < 32) ? (v0 * c + vo * s) : (v0 * c - vo * s);
        float sq = r * r;
        #pragma unroll
        for (int m = 1; m < 64; m <<= 1) sq += __shfl_xor(sq, m);
        const float scale = rsqrtf(sq * (1.0f / 64.0f) + 1e-6f);
        p[lane] = r * scale;
    } else {
        // ---- gated v ----
        const int hk = hh - (Hz + HKVz);
        float g = (lane < GATE_CHz)
                    ? x[(size_t)bt * Cz + lane] * Wgate[hk * GATE_CHz + lane]
                    : 0.0f;
        #pragma unroll
        for (int m = 1; m < 64; m <<= 1) g += __shfl_xor(g, m);
        const float gate = 2.0f / (1.0f + __expf(-g));
        float* p = row + Hz * Dz + HKVz * Dz + hk * Dz;
        p[lane] += gate * ve[(size_t)bt * (HKVz * Dz) + hk * Dz + lane];
    }
}

// ---------------------------------------------------------------------------
// Sliding-window causal attention, flash-style.
// Block = (b, h, 256-query tile). 1 query per thread, K/V chunks of 64 in LDS.
// ---------------------------------------------------------------------------
#define QB 256
#define KB 64

__global__ __launch_bounds__(256, 1) void attn_kernel(const float* __restrict__ qkv,
                                                      float* __restrict__ yout,
                                                      const int* __restrict__ winp)
{
    __shared__ float ks[KB][Dz];
    __shared__ float vs[KB][Dz];

    const int win = winp[0];
    const int tid = threadIdx.x;
    const int ntq = Tz / QB;                 // 8
    const int qt = blockIdx.x % ntq;
    const int h  = (blockIdx.x / ntq) % Hz;
    const int b  = blockIdx.x / (ntq * Hz);
    const int hk = h / (Hz / HKVz);

    const int i = qt * QB + tid;             // this thread's query position

    const float* qp = qkv + (size_t)(b * Tz + i) * QKV_N + h * Dz;
    float q[Dz];
    #pragma unroll
    for (int d4 = 0; d4 < 16; ++d4) {
        float4 t4 = *(const float4*)&qp[d4 * 4];
        q[d4*4+0] = t4.x; q[d4*4+1] = t4.y; q[d4*4+2] = t4.z; q[d4*4+3] = t4.w;
    }
    float y[Dz];
    #pragma unroll
    for (int d = 0; d < Dz; ++d) y[d] = 0.0f;
    float mrun = -1.0e30f, lrun = 0.0f;

    int j0 = qt * QB - win;
    if (j0 < 0) j0 = 0;
    j0 &= ~(KB - 1);                         // align down; masking handles rest
    const int jend = qt * QB + QB;

    const float* kbase = qkv + (size_t)(b * Tz) * QKV_N + Hz * Dz + hk * Dz;
    const float* vbase = kbase + HKVz * Dz;  // +256 floats

    for (int jc = j0; jc < jend; jc += KB) {
        // stage 64 keys + values (256 threads x 4 float4 each per matrix)
        #pragma unroll
        for (int c = 0; c < 4; ++c) {
            int idx = tid + c * 256;         // 0..1023
            int row = idx >> 4;
            int col = (idx & 15) * 4;
            size_t goff = (size_t)(jc + row) * QKV_N + col;
            *(float4*)&ks[row][col] = *(const float4*)&kbase[goff];
            *(float4*)&vs[row][col] = *(const float4*)&vbase[goff];
        }
        __syncthreads();

        for (int j = 0; j < KB; ++j) {
            const int jg = jc + j;
            const bool ok = (jg <= i) && (jg >= i - win);
            if (ok) {
                float s0 = 0.f, s1 = 0.f, s2 = 0.f, s3 = 0.f;
                #pragma unroll
                for (int d4 = 0; d4 < 16; d4 += 4) {
                    float4 k0 = *(const float4*)&ks[j][(d4+0)*4];
                    float4 k1 = *(const float4*)&ks[j][(d4+1)*4];
                    float4 k2 = *(const float4*)&ks[j][(d4+2)*4];
                    float4 k3 = *(const float4*)&ks[j][(d4+3)*4];
                    s0 = fmaf(q[(d4+0)*4+0], k0.x, s0); s0 = fmaf(q[(d4+0)*4+1], k0.y, s0);
                    s0 = fmaf(q[(d4+0)*4+2], k0.z, s0); s0 = fmaf(q[(d4+0)*4+3], k0.w, s0);
                    s1 = fmaf(q[(d4+1)*4+0], k1.x, s1); s1 = fmaf(q[(d4+1)*4+1], k1.y, s1);
                    s1 = fmaf(q[(d4+1)*4+2], k1.z, s1); s1 = fmaf(q[(d4+1)*4+3], k1.w, s1);
                    s2 = fmaf(q[(d4+2)*4+0], k2.x, s2); s2 = fmaf(q[(d4+2)*4+1], k2.y, s2);
                    s2 = fmaf(q[(d4+2)*4+2], k2.z, s2); s2 = fmaf(q[(d4+2)*4+3], k2.w, s2);
                    s3 = fmaf(q[(d4+3)*4+0], k3.x, s3); s3 = fmaf(q[(d4+3)*4+1], k3.y, s3);
                    s3 = fmaf(q[(d4+3)*4+2], k3.z, s3); s3 = fmaf(q[(d4+3)*4+3], k3.w, s3);
                }
                float s = ((s0 + s1) + (s2 + s3)) * 0.125f;
                if (s > mrun) {
                    const float corr = __expf(mrun - s);
                    lrun *= corr;
                    #pragma unroll
                    for (int d = 0; d < Dz; ++d) y[d] *= corr;
                    mrun = s;
                }
                const float e = __expf(s - mrun);
                lrun += e;
                #pragma unroll
                for (int d4 = 0; d4 < 16; ++d4) {
                    float4 v4 = *(const float4*)&vs[j][d4 * 4];
                    y[d4*4+0] = fmaf(e, v4.x, y[d4*4+0]);
                    y[d4*4+1] = fmaf(e, v4.y, y[d4*4+1]);
                    y[d4*4+2] = fmaf(e, v4.z, y[d4*4+2]);
                    y[d4*4+3] = fmaf(e, v4.w, y[d4*4+3]);
                }
            }
        }
        __syncthreads();
    }

    const float inv = 1.0f / lrun;
    float* yp = yout + (size_t)(b * Tz + i) * Cz + h * Dz;
    #pragma unroll
    for (int d4 = 0; d4 < 16; ++d4) {
        float4 o = make_float4(y[d4*4+0]*inv, y[d4*4+1]*inv, y[d4*4+2]*inv, y[d4*4+3]*inv);
        *(float4*)&yp[d4 * 4] = o;
    }
}

// ---------------------------------------------------------------------------
extern "C" void kernel_launch(void* const* d_in, const int* in_sizes, int n_in,
                              void* d_out, int out_size, void* d_ws, size_t ws_size,
                              hipStream_t stream) {
    const float* x     = (const float*)d_in[0];
    const float* ve    = (const float*)d_in[1];
    const float* cosb  = (const float*)d_in[2];
    const float* sinb  = (const float*)d_in[3];
    const float* Wq    = (const float*)d_in[4];
    const float* Wk    = (const float*)d_in[5];
    const float* Wv    = (const float*)d_in[6];
    const float* Wproj = (const float*)d_in[7];
    const float* Wgate = (const float*)d_in[8];
    const int*   winp  = (const int*)d_in[9];
    float* out = (float*)d_out;

    float* qkv  = (float*)d_ws;                        // ROWS x 1536
    float* ybuf = qkv + (size_t)ROWS * QKV_N;          // ROWS x 1024

    dim3 blk(256);

    // QKV projections into fused buffer (q | k | v)
    gemm_nt<<<dim3(Cz / BN, ROWS / BM), blk, 0, stream>>>(x, Wq, qkv, ROWS, Cz, Cz, QKV_N, 0);
    gemm_nt<<<dim3((HKVz * Dz) / BN, ROWS / BM), blk, 0, stream>>>(x, Wk, qkv, ROWS, HKVz * Dz, Cz, QKV_N, Hz * Dz);
    gemm_nt<<<dim3((HKVz * Dz) / BN, ROWS / BM), blk, 0, stream>>>(x, Wv, qkv, ROWS, HKVz * Dz, Cz, QKV_N, Hz * Dz + HKVz * Dz);

    // rope + rmsnorm + gated-v, in place
    const int n_waves = ROWS * (Hz + 2 * HKVz);
    epilogue_kernel<<<(n_waves * 64) / 256, blk, 0, stream>>>(qkv, x, ve, cosb, sinb, Wgate);

    // sliding-window attention
    attn_kernel<<<Bz * Hz * (Tz / QB), blk, 0, stream>>>(qkv, ybuf, winp);

    // output projection
    gemm_nt<<<dim3(Cz / BN, ROWS / BM), blk, 0, stream>>>(ybuf, Wproj, out, ROWS, Cz, Cz, Cz, 0);
}

// Round 3
// 852.083 us; speedup vs baseline: 1.4330x; 1.4330x over previous
//
#include <hip/hip_runtime.h>
#include <hip/hip_bf16.h>
#include <math.h>

#define Bz 2
#define Tz 2048
#define Cz 1024
#define Hz 16
#define HKVz 4
#define Dz 64
#define GATE_CHz 32
#define QKV_N 1536          // H*D + 2*HKV*D
#define ROWS (Bz*Tz)        // 4096

// ---------------------------------------------------------------------------
// GEMM (NT): Cmat[m][col_off+n] = sum_k A[m][k] * W[n][k]
// ---------------------------------------------------------------------------
#define BM 64
#define BN 64
#define BK 16

__global__ __launch_bounds__(256) void gemm_nt(const float* __restrict__ A,
                                               const float* __restrict__ W,
                                               float* __restrict__ Cmat,
                                               int M, int N, int K,
                                               int ldc, int col_off)
{
    __shared__ float As[BK][BM + 4];
    __shared__ float Ws[BK][BN + 4];

    const int tid = threadIdx.x;
    const int m0 = blockIdx.y * BM;
    const int n0 = blockIdx.x * BN;
    const int tx = tid & 15;
    const int ty = tid >> 4;

    float acc[4][4] = {};

    const int lrow = tid >> 2;
    const int lcol = (tid & 3) * 4;

    for (int k0 = 0; k0 < K; k0 += BK) {
        float4 av = *(const float4*)&A[(size_t)(m0 + lrow) * K + k0 + lcol];
        float4 wv = *(const float4*)&W[(size_t)(n0 + lrow) * K + k0 + lcol];
        As[lcol + 0][lrow] = av.x; As[lcol + 1][lrow] = av.y;
        As[lcol + 2][lrow] = av.z; As[lcol + 3][lrow] = av.w;
        Ws[lcol + 0][lrow] = wv.x; Ws[lcol + 1][lrow] = wv.y;
        Ws[lcol + 2][lrow] = wv.z; Ws[lcol + 3][lrow] = wv.w;
        __syncthreads();
        #pragma unroll
        for (int kk = 0; kk < BK; ++kk) {
            float4 a4 = *(const float4*)&As[kk][ty * 4];
            float4 w4 = *(const float4*)&Ws[kk][tx * 4];
            float aa[4] = {a4.x, a4.y, a4.z, a4.w};
            float ww[4] = {w4.x, w4.y, w4.z, w4.w};
            #pragma unroll
            for (int i = 0; i < 4; ++i)
                #pragma unroll
                for (int j = 0; j < 4; ++j)
                    acc[i][j] = fmaf(aa[i], ww[j], acc[i][j]);
        }
        __syncthreads();
    }

    #pragma unroll
    for (int i = 0; i < 4; ++i) {
        const int m = m0 + ty * 4 + i;
        float4 o = make_float4(acc[i][0], acc[i][1], acc[i][2], acc[i][3]);
        *(float4*)&Cmat[(size_t)m * ldc + col_off + n0 + tx * 4] = o;
    }
}

// ---------------------------------------------------------------------------
// Epilogue: one wave per (row, head-slot).
// ---------------------------------------------------------------------------
__global__ __launch_bounds__(256) void epilogue_kernel(float* __restrict__ qkv,
                                                       const float* __restrict__ x,
                                                       const float* __restrict__ ve,
                                                       const float* __restrict__ cosb,
                                                       const float* __restrict__ sinb,
                                                       const float* __restrict__ Wgate)
{
    const int wave = (blockIdx.x * blockDim.x + threadIdx.x) >> 6;
    const int lane = threadIdx.x & 63;
    const int NSLOT = Hz + 2 * HKVz;            // 24
    const int hh = wave % NSLOT;
    const int bt = wave / NSLOT;
    if (bt >= ROWS) return;
    const int t = bt % Tz;
    float* row = qkv + (size_t)bt * QKV_N;

    if (hh < Hz + HKVz) {
        float* p = (hh < Hz) ? (row + hh * Dz)
                             : (row + Hz * Dz + (hh - Hz) * Dz);
        float v0 = p[lane];
        float vo = p[lane ^ 32];
        const int dh = lane & 31;
        const float c = cosb[t * 32 + dh];
        const float s = sinb[t * 32 + dh];
        float r = (lane < 32) ? (v0 * c + vo * s) : (v0 * c - vo * s);
        float sq = r * r;
        #pragma unroll
        for (int m = 1; m < 64; m <<= 1) sq += __shfl_xor(sq, m);
        const float scale = rsqrtf(sq * (1.0f / 64.0f) + 1e-6f);
        p[lane] = r * scale;
    } else {
        const int hk = hh - (Hz + HKVz);
        float g = (lane < GATE_CHz)
                    ? x[(size_t)bt * Cz + lane] * Wgate[hk * GATE_CHz + lane]
                    : 0.0f;
        #pragma unroll
        for (int m = 1; m < 64; m <<= 1) g += __shfl_xor(g, m);
        const float gate = 2.0f / (1.0f + __expf(-g));
        float* p = row + Hz * Dz + HKVz * Dz + hk * Dz;
        p[lane] += gate * ve[(size_t)bt * (HKVz * Dz) + hk * Dz + lane];
    }
}

// ---------------------------------------------------------------------------
// Sliding-window causal attention, flash-style, 4-way key-split.
// Block = (b, h, 64-query tile), 256 threads = 4 groups x 64 queries.
// Group g handles keys [g*16, g*16+16) of each 64-key staged chunk.
// Since q,k are RMS-normed, ||q||=||k||=8 => |q.k/8| <= 8: use FIXED softmax
// max of 8 (no running max, no rescale, merge = plain sum).
// ---------------------------------------------------------------------------
#define QB 64
#define KB 64
#define NG 4

__global__ __launch_bounds__(256) void attn_kernel(const float* __restrict__ qkv,
                                                   float* __restrict__ yout,
                                                   const int* __restrict__ winp)
{
    __shared__ float smem[8192];        // stage: ks[64][64] | vs[64][64]; merge: yb[64][68]
    __shared__ float lsum[NG][QB];
    float* ks = smem;
    float* vs = smem + 4096;

    const int win = winp[0];
    const int tid = threadIdx.x;
    const int g  = tid >> 6;            // key-split group 0..3
    const int qi = tid & 63;            // query within tile
    const int ntq = Tz / QB;            // 32
    const int qt = blockIdx.x % ntq;
    const int h  = (blockIdx.x / ntq) % Hz;
    const int b  = blockIdx.x / (ntq * Hz);
    const int hk = h / (Hz / HKVz);
    const int i  = qt * QB + qi;        // this thread's query position

    const float* qp = qkv + (size_t)(b * Tz + i) * QKV_N + h * Dz;
    float q[Dz];
    #pragma unroll
    for (int d4 = 0; d4 < 16; ++d4) {
        float4 t4 = *(const float4*)&qp[d4 * 4];
        q[d4*4+0] = t4.x; q[d4*4+1] = t4.y; q[d4*4+2] = t4.z; q[d4*4+3] = t4.w;
    }
    float y[Dz];
    #pragma unroll
    for (int d = 0; d < Dz; ++d) y[d] = 0.0f;
    float l = 0.0f;

    int j0 = qt * QB - win;
    if (j0 < 0) j0 = 0;
    j0 &= ~(KB - 1);
    const int jend = qt * QB + QB;

    const float* kbase = qkv + (size_t)(b * Tz) * QKV_N + Hz * Dz + hk * Dz;
    const float* vbase = kbase + HKVz * Dz;

    for (int jc = j0; jc < jend; jc += KB) {
        #pragma unroll
        for (int c = 0; c < 4; ++c) {
            int idx = tid + c * 256;            // 0..1023
            int row = idx >> 4;
            int col = (idx & 15) * 4;
            size_t goff = (size_t)(jc + row) * QKV_N + col;
            *(float4*)&ks[row * 64 + col] = *(const float4*)&kbase[goff];
            *(float4*)&vs[row * 64 + col] = *(const float4*)&vbase[goff];
        }
        __syncthreads();

        for (int jj = 0; jj < 16; ++jj) {
            const int j = g * 16 + jj;
            const int jg = jc + j;
            if ((jg <= i) && (jg >= i - win)) {
                const float* kr = &ks[j * 64];
                float s0 = 0.f, s1 = 0.f, s2 = 0.f, s3 = 0.f;
                #pragma unroll
                for (int d4 = 0; d4 < 16; d4 += 4) {
                    float4 k0 = *(const float4*)&kr[(d4+0)*4];
                    float4 k1 = *(const float4*)&kr[(d4+1)*4];
                    float4 k2 = *(const float4*)&kr[(d4+2)*4];
                    float4 k3 = *(const float4*)&kr[(d4+3)*4];
                    s0 = fmaf(q[(d4+0)*4+0], k0.x, s0); s0 = fmaf(q[(d4+0)*4+1], k0.y, s0);
                    s0 = fmaf(q[(d4+0)*4+2], k0.z, s0); s0 = fmaf(q[(d4+0)*4+3], k0.w, s0);
                    s1 = fmaf(q[(d4+1)*4+0], k1.x, s1); s1 = fmaf(q[(d4+1)*4+1], k1.y, s1);
                    s1 = fmaf(q[(d4+1)*4+2], k1.z, s1); s1 = fmaf(q[(d4+1)*4+3], k1.w, s1);
                    s2 = fmaf(q[(d4+2)*4+0], k2.x, s2); s2 = fmaf(q[(d4+2)*4+1], k2.y, s2);
                    s2 = fmaf(q[(d4+2)*4+2], k2.z, s2); s2 = fmaf(q[(d4+2)*4+3], k2.w, s2);
                    s3 = fmaf(q[(d4+3)*4+0], k3.x, s3); s3 = fmaf(q[(d4+3)*4+1], k3.y, s3);
                    s3 = fmaf(q[(d4+3)*4+2], k3.z, s3); s3 = fmaf(q[(d4+3)*4+3], k3.w, s3);
                }
                const float s = ((s0 + s1) + (s2 + s3)) * 0.125f;
                const float e = __expf(s - 8.0f);   // fixed max: |s| <= 8
                l += e;
                const float* vr = &vs[j * 64];
                #pragma unroll
                for (int d4 = 0; d4 < 16; ++d4) {
                    float4 v4 = *(const float4*)&vr[d4 * 4];
                    y[d4*4+0] = fmaf(e, v4.x, y[d4*4+0]);
                    y[d4*4+1] = fmaf(e, v4.y, y[d4*4+1]);
                    y[d4*4+2] = fmaf(e, v4.z, y[d4*4+2]);
                    y[d4*4+3] = fmaf(e, v4.w, y[d4*4+3]);
                }
            }
        }
        __syncthreads();
    }

    // ---- merge 4 key-split partials (plain sums; max was fixed) ----
    lsum[g][qi] = l;
    float* yb = smem;                    // [64][68] padded
    #pragma unroll
    for (int gg = 0; gg < NG; ++gg) {
        __syncthreads();
        if (g == gg) {
            if (gg == 0) {
                #pragma unroll
                for (int d = 0; d < Dz; ++d) yb[qi * 68 + d] = y[d];
            } else {
                #pragma unroll
                for (int d = 0; d < Dz; ++d) yb[qi * 68 + d] += y[d];
            }
        }
    }
    __syncthreads();

    const float inv = 1.0f / (lsum[0][qi] + lsum[1][qi] + lsum[2][qi] + lsum[3][qi]);
    float* yp = yout + (size_t)(b * Tz + i) * Cz + h * Dz + g * 16;
    #pragma unroll
    for (int k4 = 0; k4 < 4; ++k4) {
        float4 o;
        o.x = yb[qi * 68 + g * 16 + k4 * 4 + 0] * inv;
        o.y = yb[qi * 68 + g * 16 + k4 * 4 + 1] * inv;
        o.z = yb[qi * 68 + g * 16 + k4 * 4 + 2] * inv;
        o.w = yb[qi * 68 + g * 16 + k4 * 4 + 3] * inv;
        *(float4*)&yp[k4 * 4] = o;
    }
}

// ---------------------------------------------------------------------------
extern "C" void kernel_launch(void* const* d_in, const int* in_sizes, int n_in,
                              void* d_out, int out_size, void* d_ws, size_t ws_size,
                              hipStream_t stream) {
    const float* x     = (const float*)d_in[0];
    const float* ve    = (const float*)d_in[1];
    const float* cosb  = (const float*)d_in[2];
    const float* sinb  = (const float*)d_in[3];
    const float* Wq    = (const float*)d_in[4];
    const float* Wk    = (const float*)d_in[5];
    const float* Wv    = (const float*)d_in[6];
    const float* Wproj = (const float*)d_in[7];
    const float* Wgate = (const float*)d_in[8];
    const int*   winp  = (const int*)d_in[9];
    float* out = (float*)d_out;

    float* qkv  = (float*)d_ws;                        // ROWS x 1536
    float* ybuf = qkv + (size_t)ROWS * QKV_N;          // ROWS x 1024

    dim3 blk(256);

    gemm_nt<<<dim3(Cz / BN, ROWS / BM), blk, 0, stream>>>(x, Wq, qkv, ROWS, Cz, Cz, QKV_N, 0);
    gemm_nt<<<dim3((HKVz * Dz) / BN, ROWS / BM), blk, 0, stream>>>(x, Wk, qkv, ROWS, HKVz * Dz, Cz, QKV_N, Hz * Dz);
    gemm_nt<<<dim3((HKVz * Dz) / BN, ROWS / BM), blk, 0, stream>>>(x, Wv, qkv, ROWS, HKVz * Dz, Cz, QKV_N, Hz * Dz + HKVz * Dz);

    const int n_waves = ROWS * (Hz + 2 * HKVz);
    epilogue_kernel<<<(n_waves * 64) / 256, blk, 0, stream>>>(qkv, x, ve, cosb, sinb, Wgate);

    attn_kernel<<<Bz * Hz * (Tz / QB), blk, 0, stream>>>(qkv, ybuf, winp);

    gemm_nt<<<dim3(Cz / BN, ROWS / BM), blk, 0, stream>>>(ybuf, Wproj, out, ROWS, Cz, Cz, Cz, 0);
}

// Round 5
// 295.538 us; speedup vs baseline: 4.1315x; 2.8832x over previous
//
#include <hip/hip_runtime.h>
#include <hip/hip_bf16.h>
#include <math.h>

#define Bz 2
#define Tz 2048
#define Cz 1024
#define Hz 16
#define HKVz 4
#define Dz 64
#define GATE_CHz 32
#define QKV_N 1536          // H*D + 2*HKV*D
#define ROWS (Bz*Tz)        // 4096

typedef __attribute__((ext_vector_type(8))) short bf16x8;
typedef __attribute__((ext_vector_type(4))) float f32x4;

static __device__ __forceinline__ f32x4 MFMA16(bf16x8 a, bf16x8 b, f32x4 c) {
    return __builtin_amdgcn_mfma_f32_16x16x32_bf16(a, b, c, 0, 0, 0);
}
static __device__ __forceinline__ unsigned short f2bf(float f) {
    unsigned int u = __float_as_uint(f);
    unsigned int r = (u + 0x7FFFu + ((u >> 16) & 1u)) >> 16;   // RNE
    return (unsigned short)r;
}
static __device__ __forceinline__ float bf2f(unsigned short u) {
    return __uint_as_float(((unsigned int)u) << 16);
}

// ---------------------------------------------------------------------------
// fp32 -> bf16 conversion (8 elems/thread), n % 8 == 0
// ---------------------------------------------------------------------------
__global__ __launch_bounds__(256) void cvt_bf16(const float* __restrict__ s,
                                                unsigned short* __restrict__ d, int n)
{
    int i = (blockIdx.x * 256 + threadIdx.x) * 8;
    if (i >= n) return;
    float4 a = *(const float4*)(s + i);
    float4 b = *(const float4*)(s + i + 4);
    union { unsigned short u[8]; uint4 v; } o;
    o.u[0] = f2bf(a.x); o.u[1] = f2bf(a.y); o.u[2] = f2bf(a.z); o.u[3] = f2bf(a.w);
    o.u[4] = f2bf(b.x); o.u[5] = f2bf(b.y); o.u[6] = f2bf(b.z); o.u[7] = f2bf(b.w);
    *(uint4*)(d + i) = o.v;
}

// ---------------------------------------------------------------------------
// bf16 MFMA GEMM (NT): C[m][n] = sum_k A[m][k]*B[n][k].  128x128 tile, BK=64,
// 4 waves (2x2 of 64x64), T2 XOR-swizzled LDS, register prefetch.
// Staging: thread -> one 64B half-row per matrix (full 16KB tile coverage).
// OB=1: bf16 output, OB=0: fp32 output.
// ---------------------------------------------------------------------------
template<int OB>
__global__ __launch_bounds__(256) void gemm_bf16(const unsigned short* __restrict__ A,
                                                 const unsigned short* __restrict__ Bw,
                                                 void* __restrict__ Cv, int K, int ldc)
{
    __shared__ unsigned short As[128 * 64];
    __shared__ unsigned short Bs[128 * 64];
    const int tid = threadIdx.x;
    const int wid = tid >> 6, l = tid & 63;
    const int wr = wid >> 1, wc = wid & 1;
    const int lg = l >> 4, lr = l & 15;
    const int swz = (lr & 7) << 4;

    // staging map: one contiguous 64B half-row per thread per matrix
    const int srow = tid >> 1;              // 0..127
    const int sh   = (tid & 1) * 64;        // byte offset within 128B row
    const unsigned short* Ag = A  + (size_t)(blockIdx.y * 128 + srow) * K + sh / 2;
    const unsigned short* Bg = Bw + (size_t)(blockIdx.x * 128 + srow) * K + sh / 2;

    uint4 ra[4], rb[4];
    #pragma unroll
    for (int j = 0; j < 4; ++j) {
        ra[j] = *(const uint4*)(Ag + j * 8);
        rb[j] = *(const uint4*)(Bg + j * 8);
    }

    f32x4 acc[4][4];
    #pragma unroll
    for (int m = 0; m < 4; ++m)
        #pragma unroll
        for (int n = 0; n < 4; ++n)
            acc[m][n] = (f32x4){0.f, 0.f, 0.f, 0.f};

    char* ab = (char*)As;
    char* bb = (char*)Bs;
    const int nk = K / 64;
    const int wb = srow * 128 + sh;
    const int ssw = (srow & 7) << 4;

    for (int ki = 0; ki < nk; ++ki) {
        #pragma unroll
        for (int j = 0; j < 4; ++j) {
            *(uint4*)(ab + ((wb + j * 16) ^ ssw)) = ra[j];
            *(uint4*)(bb + ((wb + j * 16) ^ ssw)) = rb[j];
        }
        __syncthreads();
        if (ki + 1 < nk) {
            const int k0 = (ki + 1) * 64;
            #pragma unroll
            for (int j = 0; j < 4; ++j) {
                ra[j] = *(const uint4*)(Ag + k0 + j * 8);
                rb[j] = *(const uint4*)(Bg + k0 + j * 8);
            }
        }
        #pragma unroll
        for (int kk = 0; kk < 2; ++kk) {
            bf16x8 av[4], bv[4];
            #pragma unroll
            for (int m = 0; m < 4; ++m)
                av[m] = *(const bf16x8*)(ab + (((wr * 64 + m * 16 + lr) * 128 + kk * 64 + lg * 16) ^ swz));
            #pragma unroll
            for (int n = 0; n < 4; ++n)
                bv[n] = *(const bf16x8*)(bb + (((wc * 64 + n * 16 + lr) * 128 + kk * 64 + lg * 16) ^ swz));
            #pragma unroll
            for (int m = 0; m < 4; ++m)
                #pragma unroll
                for (int n = 0; n < 4; ++n)
                    acc[m][n] = MFMA16(av[m], bv[n], acc[m][n]);
        }
        __syncthreads();
    }

    #pragma unroll
    for (int m = 0; m < 4; ++m)
        #pragma unroll
        for (int n = 0; n < 4; ++n)
            #pragma unroll
            for (int r = 0; r < 4; ++r) {
                const int row = blockIdx.y * 128 + wr * 64 + m * 16 + lg * 4 + r;
                const int col = blockIdx.x * 128 + wc * 64 + n * 16 + lr;
                const float v = acc[m][n][r];
                if (OB) ((unsigned short*)Cv)[(size_t)row * ldc + col] = f2bf(v);
                else    ((float*)Cv)[(size_t)row * ldc + col] = v;
            }
}

// ---------------------------------------------------------------------------
// Epilogue on bf16 qkv: one wave per (row, head-slot).
// slots 0..15 q, 16..19 k (rope+rms); 20..23 v (gate*ve add).
// ---------------------------------------------------------------------------
__global__ __launch_bounds__(256) void epilogue_kernel(unsigned short* __restrict__ qkv,
                                                       const float* __restrict__ x,
                                                       const float* __restrict__ ve,
                                                       const float* __restrict__ cosb,
                                                       const float* __restrict__ sinb,
                                                       const float* __restrict__ Wgate)
{
    const int wave = (blockIdx.x * blockDim.x + threadIdx.x) >> 6;
    const int lane = threadIdx.x & 63;
    const int NSLOT = Hz + 2 * HKVz;            // 24
    const int hh = wave % NSLOT;
    const int bt = wave / NSLOT;
    if (bt >= ROWS) return;
    const int t = bt % Tz;
    unsigned short* row = qkv + (size_t)bt * QKV_N;

    if (hh < Hz + HKVz) {
        unsigned short* p = (hh < Hz) ? (row + hh * Dz)
                                      : (row + Hz * Dz + (hh - Hz) * Dz);
        float v0 = bf2f(p[lane]);
        float vo = bf2f(p[lane ^ 32]);
        const int dh = lane & 31;
        const float c = cosb[t * 32 + dh];
        const float s = sinb[t * 32 + dh];
        float r = (lane < 32) ? (v0 * c + vo * s) : (v0 * c - vo * s);
        float sq = r * r;
        #pragma unroll
        for (int m = 1; m < 64; m <<= 1) sq += __shfl_xor(sq, m);
        const float scale = rsqrtf(sq * (1.0f / 64.0f) + 1e-6f);
        p[lane] = f2bf(r * scale);
    } else {
        const int hk = hh - (Hz + HKVz);
        float g = (lane < GATE_CHz)
                    ? x[(size_t)bt * Cz + lane] * Wgate[hk * GATE_CHz + lane]
                    : 0.0f;
        #pragma unroll
        for (int m = 1; m < 64; m <<= 1) g += __shfl_xor(g, m);
        const float gate = 2.0f / (1.0f + __expf(-g));
        unsigned short* p = row + Hz * Dz + HKVz * Dz + hk * Dz;
        p[lane] = f2bf(bf2f(p[lane]) + gate * ve[(size_t)bt * (HKVz * Dz) + hk * Dz + lane]);
    }
}

// ---------------------------------------------------------------------------
// MFMA flash attention. Block=(b, hk, 32-query tile), 4 waves = 4 GQA q-heads
// sharing staged K/V. KB=64 chunk. Fixed-max softmax (|q.k|/8 <= 8).
// S = Q*K^T (C: col=key,row=query) -> mask+exp -> P bf16 in swizzled LDS ->
// PV with V staged transposed (Vt[d][key]); denom l via ones-column MFMA.
// ---------------------------------------------------------------------------
__global__ __launch_bounds__(256) void attn_mfma(const unsigned short* __restrict__ qkv,
                                                 unsigned short* __restrict__ ybuf,
                                                 const int* __restrict__ winp)
{
    __shared__ unsigned short Ksw[64 * 64];     // [key][d] swizzled, 8KB
    __shared__ unsigned short Vtsw[64 * 64];    // [d][key] swizzled, 8KB
    __shared__ unsigned short Psw[4 * 32 * 64]; // per-wave [q][key] swizzled, 16KB
    __shared__ float lbuf[4][32];

    const int win = winp[0];
    const int tid = threadIdx.x;
    const int wid = tid >> 6, l = tid & 63;
    const int lg = l >> 4, lr = l & 15;
    const int swz = (lr & 7) << 4;

    const int qt = blockIdx.x & 63;             // T/32 = 64 tiles
    const int hk = (blockIdx.x >> 6) & 3;
    const int b  = blockIdx.x >> 8;
    const int h  = hk * 4 + wid;                // this wave's q-head

    const unsigned short* qbase = qkv + (size_t)b * Tz * QKV_N;
    const unsigned short* kvk = qbase + Hz * Dz + hk * Dz;             // +1024+hk*64
    const unsigned short* kvv = qbase + Hz * Dz + HKVz * Dz + hk * Dz; // +1280+hk*64

    // Q fragments (row=query, k=d): lane holds 8 contiguous d at lg*8
    bf16x8 aq[2][2];
    #pragma unroll
    for (int m = 0; m < 2; ++m)
        #pragma unroll
        for (int kk = 0; kk < 2; ++kk)
            aq[m][kk] = *(const bf16x8*)&qbase[(size_t)(qt * 32 + m * 16 + lr) * QKV_N
                                              + h * Dz + kk * 32 + lg * 8];

    f32x4 o[2][4], lac[2];
    #pragma unroll
    for (int m = 0; m < 2; ++m) {
        lac[m] = (f32x4){0.f, 0.f, 0.f, 0.f};
        #pragma unroll
        for (int n = 0; n < 4; ++n) o[m][n] = (f32x4){0.f, 0.f, 0.f, 0.f};
    }
    const unsigned short ov = (lr == 0) ? 0x3F80 : 0;
    const bf16x8 ones = {(short)ov,(short)ov,(short)ov,(short)ov,(short)ov,(short)ov,(short)ov,(short)ov};

    int j0 = qt * 32 - win;
    if (j0 < 0) j0 = 0;
    j0 &= ~63;
    const int jend = qt * 32 + 32;

    char* kb = (char*)Ksw;
    char* vb = (char*)Vtsw;
    char* pb = (char*)Psw + wid * 4096;

    for (int jc = j0; jc < jend; jc += 64) {
        // ---- stage K [key][d]: thread: key=tid>>2, d-block=(tid&3)*16 ----
        {
            const int key = tid >> 2, dq = (tid & 3) * 16;
            const unsigned short* g = &kvk[(size_t)(jc + key) * QKV_N + dq];
            uint4 k0 = *(const uint4*)g;
            uint4 k1 = *(const uint4*)(g + 8);
            const int base = key * 128 + dq * 2;
            const int s2 = (key & 7) << 4;
            *(uint4*)(kb + ((base) ^ s2)) = k0;
            *(uint4*)(kb + ((base + 16) ^ s2)) = k1;
        }
        // ---- stage V transposed Vt[d][key]: thread: key=tid&63, d-block=tid>>6 ----
        {
            const int key = tid & 63, db = tid >> 6;
            const unsigned short* g = &kvv[(size_t)(jc + key) * QKV_N + db * 16];
            union { unsigned short u[16]; uint4 v[2]; } vv;
            vv.v[0] = *(const uint4*)g;
            vv.v[1] = *(const uint4*)(g + 8);
            #pragma unroll
            for (int i2 = 0; i2 < 16; ++i2) {
                const int d = db * 16 + i2;
                *(unsigned short*)(vb + ((d * 128 + key * 2) ^ ((i2 & 7) << 4))) = vv.u[i2];
            }
        }
        __syncthreads();

        // ---- S = Q*K^T ----
        f32x4 s[2][4];
        #pragma unroll
        for (int m = 0; m < 2; ++m)
            #pragma unroll
            for (int n = 0; n < 4; ++n) s[m][n] = (f32x4){0.f, 0.f, 0.f, 0.f};
        #pragma unroll
        for (int kk = 0; kk < 2; ++kk) {
            bf16x8 bk[4];
            #pragma unroll
            for (int n = 0; n < 4; ++n)
                bk[n] = *(const bf16x8*)(kb + (((n * 16 + lr) * 128 + kk * 64 + lg * 16) ^ swz));
            #pragma unroll
            for (int m = 0; m < 2; ++m)
                #pragma unroll
                for (int n = 0; n < 4; ++n)
                    s[m][n] = MFMA16(aq[m][kk], bk[n], s[m][n]);
        }

        // ---- mask + exp(s/8 - 8) -> P (bf16, swizzled per-wave LDS) ----
        #pragma unroll
        for (int m = 0; m < 2; ++m)
            #pragma unroll
            for (int n = 0; n < 4; ++n)
                #pragma unroll
                for (int r = 0; r < 4; ++r) {
                    const int qrow = m * 16 + lg * 4 + r;
                    const int ig = qt * 32 + qrow;
                    const int jg = jc + n * 16 + lr;
                    float p = 0.0f;
                    if (jg <= ig && jg >= ig - win)
                        p = __expf(s[m][n][r] * 0.125f - 8.0f);
                    *(unsigned short*)(pb + ((qrow * 128 + (n * 16 + lr) * 2) ^ ((qrow & 7) << 4)))
                        = f2bf(p);
                }

        // ---- O += P*V ; l += P*ones ----
        #pragma unroll
        for (int kk = 0; kk < 2; ++kk) {
            bf16x8 ap[2], bv[4];
            #pragma unroll
            for (int m = 0; m < 2; ++m)
                ap[m] = *(const bf16x8*)(pb + (((m * 16 + lr) * 128 + kk * 64 + lg * 16) ^ swz));
            #pragma unroll
            for (int n = 0; n < 4; ++n)
                bv[n] = *(const bf16x8*)(vb + (((n * 16 + lr) * 128 + kk * 64 + lg * 16) ^ swz));
            #pragma unroll
            for (int m = 0; m < 2; ++m) {
                lac[m] = MFMA16(ap[m], ones, lac[m]);
                #pragma unroll
                for (int n = 0; n < 4; ++n)
                    o[m][n] = MFMA16(ap[m], bv[n], o[m][n]);
            }
        }
        __syncthreads();
    }

    // ---- normalize + write bf16 ----
    if (lr == 0) {
        #pragma unroll
        for (int m = 0; m < 2; ++m)
            #pragma unroll
            for (int r = 0; r < 4; ++r)
                lbuf[wid][m * 16 + lg * 4 + r] = lac[m][r];
    }
    __syncthreads();

    #pragma unroll
    for (int m = 0; m < 2; ++m)
        #pragma unroll
        for (int r = 0; r < 4; ++r) {
            const int qrow = m * 16 + lg * 4 + r;
            const float inv = 1.0f / lbuf[wid][qrow];
            #pragma unroll
            for (int n = 0; n < 4; ++n)
                ybuf[(size_t)(b * Tz + qt * 32 + qrow) * Cz + h * Dz + n * 16 + lr]
                    = f2bf(o[m][n][r] * inv);
        }
}

// ---------------------------------------------------------------------------
extern "C" void kernel_launch(void* const* d_in, const int* in_sizes, int n_in,
                              void* d_out, int out_size, void* d_ws, size_t ws_size,
                              hipStream_t stream) {
    const float* x     = (const float*)d_in[0];
    const float* ve    = (const float*)d_in[1];
    const float* cosb  = (const float*)d_in[2];
    const float* sinb  = (const float*)d_in[3];
    const float* Wq    = (const float*)d_in[4];
    const float* Wk    = (const float*)d_in[5];
    const float* Wv    = (const float*)d_in[6];
    const float* Wproj = (const float*)d_in[7];
    const float* Wgate = (const float*)d_in[8];
    const int*   winp  = (const int*)d_in[9];
    float* out = (float*)d_out;

    char* w = (char*)d_ws;
    unsigned short* xb    = (unsigned short*)w;  w += (size_t)ROWS * Cz * 2;      // 8 MB
    unsigned short* Wqkvb = (unsigned short*)w;  w += (size_t)QKV_N * Cz * 2;     // 3 MB
    unsigned short* Wpb   = (unsigned short*)w;  w += (size_t)Cz * Cz * 2;        // 2 MB
    unsigned short* qkvb  = (unsigned short*)w;  w += (size_t)ROWS * QKV_N * 2;   // 12 MB
    unsigned short* ybb   = (unsigned short*)w;  w += (size_t)ROWS * Cz * 2;      // 8 MB

    dim3 blk(256);
    auto cvt = [&](const float* s, unsigned short* d, int n) {
        cvt_bf16<<<(n / 8 + 255) / 256, blk, 0, stream>>>(s, d, n);
    };
    cvt(x, xb, ROWS * Cz);
    cvt(Wq, Wqkvb, Hz * Dz * Cz);
    cvt(Wk, Wqkvb + (size_t)(Hz * Dz) * Cz, HKVz * Dz * Cz);
    cvt(Wv, Wqkvb + (size_t)(Hz * Dz + HKVz * Dz) * Cz, HKVz * Dz * Cz);
    cvt(Wproj, Wpb, Cz * Cz);

    // fused QKV projection: [4096 x 1024] x [1536 x 1024]^T -> bf16 qkv
    gemm_bf16<1><<<dim3(QKV_N / 128, ROWS / 128), blk, 0, stream>>>(xb, Wqkvb, qkvb, Cz, QKV_N);

    // rope + rmsnorm + gated-v, in place on bf16
    const int n_waves = ROWS * (Hz + 2 * HKVz);
    epilogue_kernel<<<(n_waves * 64) / 256, blk, 0, stream>>>(qkvb, x, ve, cosb, sinb, Wgate);

    // MFMA flash attention -> bf16 ybuf
    attn_mfma<<<Bz * HKVz * (Tz / 32), blk, 0, stream>>>(qkvb, ybb, winp);

    // output projection: [4096 x 1024] x [1024 x 1024]^T -> fp32 out
    gemm_bf16<0><<<dim3(Cz / 128, ROWS / 128), blk, 0, stream>>>(ybb, Wpb, out, Cz, Cz);
}